// Round 1
// baseline (652.369 us; speedup 1.0000x reference)
//
#include <hip/hip_runtime.h>

#define NBATCH 4
#define NN 2048
#define NR 8192            // NBATCH*NN rows
#define CH 16              // m-chunks per row
#define CM 128             // m per chunk (NN/CH)
#define TOPK 10

// ---------------- K1: encoders + fusion + q/k projection ----------------
// One wave (64 lanes) per (b,n) row; 4 rows per block.
__global__ __launch_bounds__(256) void k1_encode(
    const float* __restrict__ xd, const float* __restrict__ xs,
    const float* __restrict__ Wd, const float* __restrict__ bd,
    const float* __restrict__ Ws, const float* __restrict__ bs,
    const float* __restrict__ Wf, const float* __restrict__ bf,
    const float* __restrict__ Wq, const float* __restrict__ Wk,
    float* __restrict__ qg, float* __restrict__ kg)
{
    int wave = threadIdx.x >> 6;
    int lane = threadIdx.x & 63;
    int r = blockIdx.x * 4 + wave;        // 0..8191

    __shared__ float xm[4][16];
    __shared__ float xst[4][8];
    __shared__ float hc[4][128];
    __shared__ float hh[4][64];

    // mean over T of x_dyn[b,n,:,:]  (T=32, Dd=16, 512 floats, coalesced)
    const float* xdr = xd + (size_t)r * 512;
    float acc = 0.f;
    #pragma unroll
    for (int j = 0; j < 8; ++j) acc += xdr[lane + 64*j];   // d = lane%16 fixed
    acc += __shfl_xor(acc, 16);
    acc += __shfl_xor(acc, 32);
    if (lane < 16) xm[wave][lane] = acc * (1.0f/32.0f);
    if (lane < 8)  xst[wave][lane] = xs[(size_t)r*8 + lane];
    __syncthreads();

    float a1 = bd[lane];
    #pragma unroll
    for (int d = 0; d < 16; ++d) a1 += xm[wave][d] * Wd[d*64 + lane];
    a1 = fmaxf(a1, 0.f);
    float a2 = bs[lane];
    #pragma unroll
    for (int d = 0; d < 8; ++d) a2 += xst[wave][d] * Ws[d*64 + lane];
    a2 = fmaxf(a2, 0.f);
    hc[wave][lane] = a1;
    hc[wave][64 + lane] = a2;
    __syncthreads();

    float hv = bf[lane];
    #pragma unroll
    for (int j = 0; j < 128; ++j) hv += hc[wave][j] * Wf[j*64 + lane];
    hh[wave][lane] = hv;
    __syncthreads();

    float qv = 0.f, kv = 0.f;
    #pragma unroll
    for (int j = 0; j < 64; ++j) {
        float hj = hh[wave][j];
        qv += hj * Wq[j*64 + lane];
        kv += hj * Wk[j*64 + lane];
    }
    qg[(size_t)r*64 + lane] = qv;
    kg[(size_t)r*64 + lane] = kv;
}

// ---------------- K2a: per-(row,chunk) online softmax stats ----------------
// Thread owns one row (q in registers) over a 128-wide m chunk.
// k addresses are wave-uniform (b, m derived from blockIdx/loop) -> scalar-friendly.
__global__ __launch_bounds__(256) void k2a_stats(
    const float* __restrict__ qg, const float* __restrict__ kg,
    float* __restrict__ pM, float* __restrict__ pS)
{
    int tile = blockIdx.x >> 4;          // 0..31 : row tile of 256
    int ch   = blockIdx.x & 15;          // m chunk
    int r = tile * 256 + threadIdx.x;
    int b = tile >> 3;                   // uniform: 8 tiles per batch

    float q[64];
    const float* qrow = qg + (size_t)r * 64;
    #pragma unroll
    for (int c = 0; c < 64; ++c) q[c] = qrow[c];

    const float4* kb = (const float4*)(kg + (size_t)b * NN * 64);

    float M[4] = {-3e38f,-3e38f,-3e38f,-3e38f};
    float S[4] = {0.f,0.f,0.f,0.f};

    for (int mi = 0; mi < CM; ++mi) {
        const float4* kr = kb + (size_t)(ch*CM + mi) * 16;
        float s[4] = {0.f,0.f,0.f,0.f};
        #pragma unroll
        for (int h = 0; h < 4; ++h) {
            #pragma unroll
            for (int c4 = 0; c4 < 4; ++c4) {
                float4 kvv = kr[h*4 + c4];
                int cb = h*16 + c4*4;
                s[h] += kvv.x*q[cb] + kvv.y*q[cb+1] + kvv.z*q[cb+2] + kvv.w*q[cb+3];
            }
        }
        #pragma unroll
        for (int h = 0; h < 4; ++h) {
            float sc = s[h] * 0.25f;                 // / sqrt(16)
            float nM = fmaxf(M[h], sc);
            S[h] = S[h] * __expf(M[h] - nM) + __expf(sc - nM);
            M[h] = nM;
        }
    }
    #pragma unroll
    for (int h = 0; h < 4; ++h) {
        pM[(size_t)(ch*4 + h) * NR + r] = M[h];
        pS[(size_t)(ch*4 + h) * NR + r] = S[h];
    }
}

// ---------------- K2b: merge chunk stats -> final (max, 1/sum) per head ----
__global__ __launch_bounds__(256) void k2b_merge(
    const float* __restrict__ pM, const float* __restrict__ pS,
    float* __restrict__ Mf, float* __restrict__ Rf)
{
    int r = blockIdx.x * 256 + threadIdx.x;
    #pragma unroll
    for (int h = 0; h < 4; ++h) {
        float mc[CH];
        float M = -3e38f;
        #pragma unroll
        for (int c = 0; c < CH; ++c) {
            mc[c] = pM[(size_t)(c*4 + h) * NR + r];
            M = fmaxf(M, mc[c]);
        }
        float S = 0.f;
        #pragma unroll
        for (int c = 0; c < CH; ++c)
            S += pS[(size_t)(c*4 + h) * NR + r] * __expf(mc[c] - M);
        Mf[(size_t)h * NR + r] = M;
        Rf[(size_t)h * NR + r] = 1.0f / S;
    }
}

// ---------------- K2c: recompute scores, per-chunk top-10 -------------------
__global__ __launch_bounds__(256) void k2c_topk(
    const float* __restrict__ qg, const float* __restrict__ kg,
    const float* __restrict__ Mf, const float* __restrict__ Rf,
    float* __restrict__ tV, int* __restrict__ tI)
{
    int tile = blockIdx.x >> 4;
    int ch   = blockIdx.x & 15;
    int r = tile * 256 + threadIdx.x;
    int b = tile >> 3;

    float q[64];
    const float* qrow = qg + (size_t)r * 64;
    #pragma unroll
    for (int c = 0; c < 64; ++c) q[c] = qrow[c];

    float Mh[4], Rh[4];
    #pragma unroll
    for (int h = 0; h < 4; ++h) {
        Mh[h] = Mf[(size_t)h * NR + r];
        Rh[h] = Rf[(size_t)h * NR + r];
    }

    const float4* kb = (const float4*)(kg + (size_t)b * NN * 64);

    float tv[TOPK]; int ti[TOPK];
    #pragma unroll
    for (int s = 0; s < TOPK; ++s) { tv[s] = -3e38f; ti[s] = 0; }

    for (int mi = 0; mi < CM; ++mi) {
        int m = ch*CM + mi;
        const float4* kr = kb + (size_t)m * 16;
        float s4[4] = {0.f,0.f,0.f,0.f};
        #pragma unroll
        for (int h = 0; h < 4; ++h) {
            #pragma unroll
            for (int c4 = 0; c4 < 4; ++c4) {
                float4 kvv = kr[h*4 + c4];
                int cb = h*16 + c4*4;
                s4[h] += kvv.x*q[cb] + kvv.y*q[cb+1] + kvv.z*q[cb+2] + kvv.w*q[cb+3];
            }
        }
        float v = 0.f;
        #pragma unroll
        for (int h = 0; h < 4; ++h)
            v += __expf(s4[h]*0.25f - Mh[h]) * Rh[h];
        v *= 0.25f;                                   // mean over heads
        if (v > tv[TOPK-1]) {                         // branchless bubble insert
            float cv = v; int ci = m;
            #pragma unroll
            for (int s = 0; s < TOPK; ++s) {
                bool ins = cv > tv[s];                // strict > : stable ties
                float ov = tv[s]; int oi = ti[s];
                tv[s] = ins ? cv : ov;  ti[s] = ins ? ci : oi;
                cv    = ins ? ov : cv;  ci    = ins ? oi : ci;
            }
        }
    }
    #pragma unroll
    for (int s = 0; s < TOPK; ++s) {
        tV[(size_t)(ch*TOPK + s) * NR + r] = tv[s];
        tI[(size_t)(ch*TOPK + s) * NR + r] = ti[s];
    }
}

// ---------------- K2d: merge 16 chunk top-10 lists -> final top-10 ----------
__global__ __launch_bounds__(256) void k2d_final(
    const float* __restrict__ tV, const int* __restrict__ tI,
    float* __restrict__ fV, int* __restrict__ fI)
{
    int r = blockIdx.x * 256 + threadIdx.x;
    float tv[TOPK]; int ti[TOPK];
    #pragma unroll
    for (int s = 0; s < TOPK; ++s) { tv[s] = -3e38f; ti[s] = 0; }
    for (int c = 0; c < CH; ++c) {                  // ascending m order
        #pragma unroll
        for (int s = 0; s < TOPK; ++s) {
            float cv = tV[(size_t)(c*TOPK + s) * NR + r];
            int   ci = tI[(size_t)(c*TOPK + s) * NR + r];
            if (cv > tv[TOPK-1]) {
                #pragma unroll
                for (int s2 = 0; s2 < TOPK; ++s2) {
                    bool ins = cv > tv[s2];
                    float ov = tv[s2]; int oi = ti[s2];
                    tv[s2] = ins ? cv : ov;  ti[s2] = ins ? ci : oi;
                    cv     = ins ? ov : cv;  ci     = ins ? oi : ci;
                }
            }
        }
    }
    #pragma unroll
    for (int s = 0; s < TOPK; ++s) {
        fV[(size_t)s * NR + r] = tv[s];
        fI[(size_t)s * NR + r] = ti[s];
    }
}

// ---------------- K3: A_final base = 0.3*prior; L = -A; degree row-sums -----
__global__ __launch_bounds__(256) void k3_base(
    const float* __restrict__ prior, float* __restrict__ Lout,
    float* __restrict__ Aout, float* __restrict__ deg)
{
    int r = blockIdx.x;                  // one row per block
    const float4* pr = (const float4*)(prior + (size_t)r * NN);
    float4* Ar = (float4*)(Aout + (size_t)r * NN);
    float4* Lr = (float4*)(Lout + (size_t)r * NN);
    float sum = 0.f;
    for (int i = threadIdx.x; i < NN/4; i += 256) {
        float4 p = pr[i];
        float4 a; a.x = 0.3f*p.x; a.y = 0.3f*p.y; a.z = 0.3f*p.z; a.w = 0.3f*p.w;
        Ar[i] = a;
        float4 l; l.x = -a.x; l.y = -a.y; l.z = -a.z; l.w = -a.w;
        Lr[i] = l;
        sum += a.x + a.y + a.z + a.w;
    }
    #pragma unroll
    for (int o = 32; o > 0; o >>= 1) sum += __shfl_down(sum, o);
    __shared__ float wsum[4];
    if ((threadIdx.x & 63) == 0) wsum[threadIdx.x >> 6] = sum;
    __syncthreads();
    if (threadIdx.x == 0) deg[r] = wsum[0] + wsum[1] + wsum[2] + wsum[3];
}

// ---------------- K4: scatter symmetric sparse top-k contributions ----------
__global__ __launch_bounds__(256) void k4_scatter(
    const float* __restrict__ fV, const int* __restrict__ fI,
    float* __restrict__ Lout, float* __restrict__ Aout, float* __restrict__ deg)
{
    int r = blockIdx.x * 256 + threadIdx.x;
    int b = r >> 11;
    int n = r & 2047;
    float dsum = 0.f;
    #pragma unroll
    for (int s = 0; s < TOPK; ++s) {
        float w = 0.35f * fV[(size_t)s * NR + r];    // 0.7 * 0.5 * val
        int j = fI[(size_t)s * NR + r];
        size_t ij = (size_t)r * NN + j;
        size_t ji = ((size_t)(b * NN + j)) * NN + n;
        atomicAdd(&Aout[ij],  w);
        atomicAdd(&Aout[ji],  w);
        atomicAdd(&Lout[ij], -w);
        atomicAdd(&Lout[ji], -w);
        atomicAdd(&deg[b * NN + j], w);
        dsum += w;
    }
    atomicAdd(&deg[r], dsum);
}

// ---------------- K5: L diagonal += degree ---------------------------------
__global__ __launch_bounds__(256) void k5_diag(
    const float* __restrict__ deg, float* __restrict__ Lout)
{
    int r = blockIdx.x * 256 + threadIdx.x;
    Lout[(size_t)r * NN + (r & 2047)] += deg[r];
}

extern "C" void kernel_launch(void* const* d_in, const int* in_sizes, int n_in,
                              void* d_out, int out_size, void* d_ws, size_t ws_size,
                              hipStream_t stream)
{
    const float* xd    = (const float*)d_in[0];
    const float* xs    = (const float*)d_in[1];
    const float* prior = (const float*)d_in[2];
    const float* Wd    = (const float*)d_in[3];
    const float* bd    = (const float*)d_in[4];
    const float* Ws    = (const float*)d_in[5];
    const float* bs    = (const float*)d_in[6];
    const float* Wf    = (const float*)d_in[7];
    const float* bf    = (const float*)d_in[8];
    const float* Wq    = (const float*)d_in[9];
    const float* Wk    = (const float*)d_in[10];

    float* Lout = (float*)d_out;
    float* Aout = Lout + (size_t)NR * NN;

    float* w  = (float*)d_ws;
    float* qg = w;        w += (size_t)NR * 64;
    float* kg = w;        w += (size_t)NR * 64;
    float* pM = w;        w += (size_t)CH * 4 * NR;
    float* pS = w;        w += (size_t)CH * 4 * NR;
    float* Mf = w;        w += (size_t)4 * NR;
    float* Rf = w;        w += (size_t)4 * NR;
    float* tV = w;        w += (size_t)CH * TOPK * NR;
    int*   tI = (int*)w;  w += (size_t)CH * TOPK * NR;
    float* fV = w;        w += (size_t)TOPK * NR;
    int*   fI = (int*)w;  w += (size_t)TOPK * NR;
    float* deg = w;       w += NR;
    // total ws use: ~19.8 MB

    k1_encode<<<NR/4, 256, 0, stream>>>(xd, xs, Wd, bd, Ws, bs, Wf, bf, Wq, Wk, qg, kg);
    k2a_stats<<<(NR/256)*CH, 256, 0, stream>>>(qg, kg, pM, pS);
    k2b_merge<<<NR/256, 256, 0, stream>>>(pM, pS, Mf, Rf);
    k2c_topk<<<(NR/256)*CH, 256, 0, stream>>>(qg, kg, Mf, Rf, tV, tI);
    k2d_final<<<NR/256, 256, 0, stream>>>(tV, tI, fV, fI);
    k3_base<<<NR, 256, 0, stream>>>(prior, Lout, Aout, deg);
    k4_scatter<<<NR/256, 256, 0, stream>>>(fV, fI, Lout, Aout, deg);
    k5_diag<<<NR/256, 256, 0, stream>>>(deg, Lout);
}

// Round 2
// 388.327 us; speedup vs baseline: 1.6799x; 1.6799x over previous
//
#include <hip/hip_runtime.h>

#define NBATCH 4
#define NN 2048
#define NR 8192            // NBATCH*NN rows
#define TOPK 10

typedef __attribute__((ext_vector_type(4))) float f32x4;
typedef __attribute__((ext_vector_type(8))) short bf16x8;

__device__ inline unsigned short f2bf(float x) {
    unsigned u = __float_as_uint(x);
    unsigned r = (u + 0x7FFF + ((u >> 16) & 1)) >> 16;
    return (unsigned short)r;
}
__device__ inline float bf2f(unsigned short u) {
    return __uint_as_float(((unsigned)u) << 16);
}
__device__ inline unsigned long long shfl_xor_u64(unsigned long long x, int d) {
    unsigned lo = (unsigned)x, hi = (unsigned)(x >> 32);
    lo = __shfl_xor(lo, d); hi = __shfl_xor(hi, d);
    return ((unsigned long long)hi << 32) | lo;
}

// ---------------- K1: encoders + fusion + q/k projection (bf16, K=32 padded)
__global__ __launch_bounds__(256) void k1_encode(
    const float* __restrict__ xd, const float* __restrict__ xs,
    const float* __restrict__ Wd, const float* __restrict__ bd,
    const float* __restrict__ Ws, const float* __restrict__ bs,
    const float* __restrict__ Wf, const float* __restrict__ bf,
    const float* __restrict__ Wq, const float* __restrict__ Wk,
    unsigned short* __restrict__ qh, unsigned short* __restrict__ kh)
{
    int wave = threadIdx.x >> 6;
    int lane = threadIdx.x & 63;
    int r = blockIdx.x * 4 + wave;        // 0..8191

    __shared__ float xm[4][16];
    __shared__ float xst[4][8];
    __shared__ float hc[4][128];
    __shared__ float hh[4][64];

    const float* xdr = xd + (size_t)r * 512;
    float acc = 0.f;
    #pragma unroll
    for (int j = 0; j < 8; ++j) acc += xdr[lane + 64*j];
    acc += __shfl_xor(acc, 16);
    acc += __shfl_xor(acc, 32);
    if (lane < 16) xm[wave][lane] = acc * (1.0f/32.0f);
    if (lane < 8)  xst[wave][lane] = xs[(size_t)r*8 + lane];
    __syncthreads();

    float a1 = bd[lane];
    #pragma unroll
    for (int d = 0; d < 16; ++d) a1 += xm[wave][d] * Wd[d*64 + lane];
    a1 = fmaxf(a1, 0.f);
    float a2 = bs[lane];
    #pragma unroll
    for (int d = 0; d < 8; ++d) a2 += xst[wave][d] * Ws[d*64 + lane];
    a2 = fmaxf(a2, 0.f);
    hc[wave][lane] = a1;
    hc[wave][64 + lane] = a2;
    __syncthreads();

    float hv = bf[lane];
    #pragma unroll
    for (int j = 0; j < 128; ++j) hv += hc[wave][j] * Wf[j*64 + lane];
    hh[wave][lane] = hv;
    __syncthreads();

    float qv = 0.f, kv = 0.f;
    #pragma unroll
    for (int j = 0; j < 64; ++j) {
        float hj = hh[wave][j];
        qv += hj * Wq[j*64 + lane];
        kv += hj * Wk[j*64 + lane];
    }
    // lane = head*16 + dim; layout qh[(b*4+h)*2048 + n][32], dims 16..31 = 0
    int b = r >> 11, n = r & 2047;
    int head = lane >> 4, dim = lane & 15;
    size_t base = ((size_t)(b*4 + head) * NN + n) * 32;
    qh[base + dim] = f2bf(qv);
    qh[base + 16 + dim] = 0;
    kh[base + dim] = f2bf(kv);
    kh[base + 16 + dim] = 0;
}

// ---------------- K2A: per-(b,h,row) softmax stats via MFMA (2 sweeps) ------
__global__ __launch_bounds__(256) void k2A_stats(
    const unsigned short* __restrict__ qh, const unsigned short* __restrict__ kh,
    float* __restrict__ Mf, float* __restrict__ Rf)
{
    const float C1 = 0.36067376022224085f;   // 0.25 * log2(e)
    int bh = blockIdx.x >> 7;                // 16 (b,h) pairs
    int rg = blockIdx.x & 127;               // row group of 16
    int w = threadIdx.x >> 6, l = threadIdx.x & 63;
    int quad = l >> 4, lo = l & 15;

    bf16x8 afrag = *(const bf16x8*)(qh + ((size_t)bh * NN + rg*16 + lo) * 32 + quad*8);
    const unsigned short* kbase = kh + (size_t)bh * NN * 32;

    __shared__ float redA[4][16];
    __shared__ float Mrow[16];

    float Mloc[4] = {-3e38f,-3e38f,-3e38f,-3e38f};
    for (int t = 0; t < 32; ++t) {
        int m0 = w*512 + t*16;
        bf16x8 bfrag = *(const bf16x8*)(kbase + (size_t)(m0 + lo) * 32 + quad*8);
        f32x4 acc = {0.f,0.f,0.f,0.f};
        acc = __builtin_amdgcn_mfma_f32_16x16x32_bf16(afrag, bfrag, acc, 0, 0, 0);
        #pragma unroll
        for (int rr = 0; rr < 4; ++rr) Mloc[rr] = fmaxf(Mloc[rr], acc[rr]);
    }
    #pragma unroll
    for (int d = 1; d <= 8; d <<= 1) {
        #pragma unroll
        for (int rr = 0; rr < 4; ++rr) Mloc[rr] = fmaxf(Mloc[rr], __shfl_xor(Mloc[rr], d));
    }
    if (lo == 0) {
        #pragma unroll
        for (int rr = 0; rr < 4; ++rr) redA[w][quad*4 + rr] = Mloc[rr];
    }
    __syncthreads();
    if (threadIdx.x < 16)
        Mrow[threadIdx.x] = fmaxf(fmaxf(redA[0][threadIdx.x], redA[1][threadIdx.x]),
                                  fmaxf(redA[2][threadIdx.x], redA[3][threadIdx.x]));
    __syncthreads();

    float mrr[4];
    #pragma unroll
    for (int rr = 0; rr < 4; ++rr) mrr[rr] = Mrow[quad*4 + rr];

    float Sloc[4] = {0.f,0.f,0.f,0.f};
    for (int t = 0; t < 32; ++t) {
        int m0 = w*512 + t*16;
        bf16x8 bfrag = *(const bf16x8*)(kbase + (size_t)(m0 + lo) * 32 + quad*8);
        f32x4 acc = {0.f,0.f,0.f,0.f};
        acc = __builtin_amdgcn_mfma_f32_16x16x32_bf16(afrag, bfrag, acc, 0, 0, 0);
        #pragma unroll
        for (int rr = 0; rr < 4; ++rr)
            Sloc[rr] += exp2f((acc[rr] - mrr[rr]) * C1);
    }
    #pragma unroll
    for (int d = 1; d <= 8; d <<= 1) {
        #pragma unroll
        for (int rr = 0; rr < 4; ++rr) Sloc[rr] += __shfl_xor(Sloc[rr], d);
    }
    if (lo == 0) {
        #pragma unroll
        for (int rr = 0; rr < 4; ++rr) redA[w][quad*4 + rr] = Sloc[rr];
    }
    __syncthreads();
    if (threadIdx.x < 16) {
        float S = redA[0][threadIdx.x] + redA[1][threadIdx.x]
                + redA[2][threadIdx.x] + redA[3][threadIdx.x];
        int row = rg*16 + threadIdx.x;
        Mf[(size_t)bh * NN + row] = 0.25f * Mrow[threadIdx.x];
        Rf[(size_t)bh * NN + row] = 1.0f / S;
    }
}

// ---------------- K2C: head-averaged values via MFMA + exact top-10 ---------
__global__ __launch_bounds__(256) void k2C_topk(
    const unsigned short* __restrict__ qh, const unsigned short* __restrict__ kh,
    const float* __restrict__ Mf, const float* __restrict__ Rf,
    float* __restrict__ fV, int* __restrict__ fI)
{
    const float C1 = 0.36067376022224085f;   // 0.25 * log2(e)
    const float L2E = 1.4426950408889634f;
    int b  = blockIdx.x >> 7;
    int rg = blockIdx.x & 127;
    int w = threadIdx.x >> 6, l = threadIdx.x & 63;
    int quad = l >> 4, lo = l & 15;

    __shared__ unsigned short vt[16][2048];  // bf16 values, XOR-swizzled cols

    bf16x8 afrag[4];
    float b2[4][4], r4[4][4];
    #pragma unroll
    for (int h = 0; h < 4; ++h) {
        int bh = b*4 + h;
        afrag[h] = *(const bf16x8*)(qh + ((size_t)bh * NN + rg*16 + lo) * 32 + quad*8);
        #pragma unroll
        for (int rr = 0; rr < 4; ++rr) {
            int row = rg*16 + quad*4 + rr;
            b2[h][rr] = Mf[(size_t)bh * NN + row] * L2E;
            r4[h][rr] = Rf[(size_t)bh * NN + row] * 0.25f;
        }
    }

    int swz_w = quad << 4;                   // write swizzle = (row>>2)*16
    for (int t = 0; t < 32; ++t) {
        int m0 = w*512 + t*16;
        float vacc[4] = {0.f,0.f,0.f,0.f};
        #pragma unroll
        for (int h = 0; h < 4; ++h) {
            bf16x8 bfrag = *(const bf16x8*)(kh + ((size_t)(b*4+h) * NN + m0 + lo) * 32 + quad*8);
            f32x4 acc = {0.f,0.f,0.f,0.f};
            acc = __builtin_amdgcn_mfma_f32_16x16x32_bf16(afrag[h], bfrag, acc, 0, 0, 0);
            #pragma unroll
            for (int rr = 0; rr < 4; ++rr) {
                float e = exp2f(fmaf(acc[rr], C1, -b2[h][rr]));
                vacc[rr] = fmaf(e, r4[h][rr], vacc[rr]);
            }
        }
        #pragma unroll
        for (int rr = 0; rr < 4; ++rr)
            vt[quad*4 + rr][(m0 + lo) ^ swz_w] = f2bf(vacc[rr]);
    }
    __syncthreads();

    // top-10 per row; wave w handles rows 4w..4w+3
    for (int rr = 0; rr < 4; ++rr) {
        int row = w*4 + rr;
        int swz = (row >> 2) << 4;
        float tv[TOPK]; int ti[TOPK];
        #pragma unroll
        for (int s = 0; s < TOPK; ++s) { tv[s] = -3e38f; ti[s] = 0; }
        for (int j = 0; j < 16; ++j) {
            int m1 = 2*l + 128*j;
            unsigned pair = *(const unsigned*)&vt[row][m1 ^ swz];
            #pragma unroll
            for (int half = 0; half < 2; ++half) {
                float v = bf2f((unsigned short)(half ? (pair >> 16) : (pair & 0xFFFF)));
                int m = m1 + half;
                if (v > tv[TOPK-1]) {
                    float cv = v; int ci = m;
                    #pragma unroll
                    for (int s = 0; s < TOPK; ++s) {
                        bool ins = cv > tv[s];
                        float ov = tv[s]; int oi = ti[s];
                        tv[s] = ins ? cv : ov;  ti[s] = ins ? ci : oi;
                        cv    = ins ? ov : cv;  ci    = ins ? oi : ci;
                    }
                }
            }
        }
        // 10 rounds of 64-lane argmax on packed (value, 2047-idx) keys
        int rowg = b * NN + rg*16 + row;
        #pragma unroll 1
        for (int s = 0; s < TOPK; ++s) {
            unsigned vb = __float_as_uint(fmaxf(tv[0], 0.0f));
            unsigned long long key =
                ((unsigned long long)vb << 12) | (unsigned)(2047 - ti[0]);
            unsigned long long kmax = key;
            #pragma unroll
            for (int d = 1; d < 64; d <<= 1) {
                unsigned long long o = shfl_xor_u64(kmax, d);
                kmax = (o > kmax) ? o : kmax;
            }
            if (key == kmax) {   // winner pops its head
                #pragma unroll
                for (int q = 0; q < TOPK-1; ++q) { tv[q] = tv[q+1]; ti[q] = ti[q+1]; }
                tv[TOPK-1] = -3e38f; ti[TOPK-1] = 0;
            }
            if (l == 0) {
                fV[(size_t)s * NR + rowg] = __uint_as_float((unsigned)(kmax >> 12));
                fI[(size_t)s * NR + rowg] = 2047 - (int)(kmax & 0xFFF);
            }
        }
    }
}

// ---------------- K3: A_final base = 0.3*prior; L = -A; degree row-sums -----
__global__ __launch_bounds__(256) void k3_base(
    const float* __restrict__ prior, float* __restrict__ Lout,
    float* __restrict__ Aout, float* __restrict__ deg)
{
    int r = blockIdx.x;
    const float4* pr = (const float4*)(prior + (size_t)r * NN);
    float4* Ar = (float4*)(Aout + (size_t)r * NN);
    float4* Lr = (float4*)(Lout + (size_t)r * NN);
    float sum = 0.f;
    for (int i = threadIdx.x; i < NN/4; i += 256) {
        float4 p = pr[i];
        float4 a; a.x = 0.3f*p.x; a.y = 0.3f*p.y; a.z = 0.3f*p.z; a.w = 0.3f*p.w;
        Ar[i] = a;
        float4 lv; lv.x = -a.x; lv.y = -a.y; lv.z = -a.z; lv.w = -a.w;
        Lr[i] = lv;
        sum += a.x + a.y + a.z + a.w;
    }
    #pragma unroll
    for (int o = 32; o > 0; o >>= 1) sum += __shfl_down(sum, o);
    __shared__ float wsum[4];
    if ((threadIdx.x & 63) == 0) wsum[threadIdx.x >> 6] = sum;
    __syncthreads();
    if (threadIdx.x == 0) deg[r] = wsum[0] + wsum[1] + wsum[2] + wsum[3];
}

// ---------------- K4: scatter symmetric sparse top-k contributions ----------
__global__ __launch_bounds__(256) void k4_scatter(
    const float* __restrict__ fV, const int* __restrict__ fI,
    float* __restrict__ Lout, float* __restrict__ Aout, float* __restrict__ deg)
{
    int r = blockIdx.x * 256 + threadIdx.x;
    int b = r >> 11;
    int n = r & 2047;
    float dsum = 0.f;
    #pragma unroll
    for (int s = 0; s < TOPK; ++s) {
        float wv = 0.35f * fV[(size_t)s * NR + r];   // 0.7 * 0.5 * val
        int j = fI[(size_t)s * NR + r];
        size_t ij = (size_t)r * NN + j;
        size_t ji = ((size_t)(b * NN + j)) * NN + n;
        atomicAdd(&Aout[ij],  wv);
        atomicAdd(&Aout[ji],  wv);
        atomicAdd(&Lout[ij], -wv);
        atomicAdd(&Lout[ji], -wv);
        atomicAdd(&deg[b * NN + j], wv);
        dsum += wv;
    }
    atomicAdd(&deg[r], dsum);
}

// ---------------- K5: L diagonal += degree ---------------------------------
__global__ __launch_bounds__(256) void k5_diag(
    const float* __restrict__ deg, float* __restrict__ Lout)
{
    int r = blockIdx.x * 256 + threadIdx.x;
    Lout[(size_t)r * NN + (r & 2047)] += deg[r];
}

extern "C" void kernel_launch(void* const* d_in, const int* in_sizes, int n_in,
                              void* d_out, int out_size, void* d_ws, size_t ws_size,
                              hipStream_t stream)
{
    const float* xd    = (const float*)d_in[0];
    const float* xs    = (const float*)d_in[1];
    const float* prior = (const float*)d_in[2];
    const float* Wd    = (const float*)d_in[3];
    const float* bd    = (const float*)d_in[4];
    const float* Ws    = (const float*)d_in[5];
    const float* bs    = (const float*)d_in[6];
    const float* Wf    = (const float*)d_in[7];
    const float* bf    = (const float*)d_in[8];
    const float* Wq    = (const float*)d_in[9];
    const float* Wk    = (const float*)d_in[10];

    float* Lout = (float*)d_out;
    float* Aout = Lout + (size_t)NR * NN;

    unsigned short* qh = (unsigned short*)d_ws;          // 16*2048*32 bf16 = 2MB
    unsigned short* kh = qh + (size_t)16 * NN * 32;      // 2MB
    float* Mf  = (float*)(kh + (size_t)16 * NN * 32);    // 16*2048
    float* Rf  = Mf + (size_t)16 * NN;
    float* fV  = Rf + (size_t)16 * NN;                   // 10*8192
    int*   fI  = (int*)(fV + (size_t)TOPK * NR);
    float* deg = (float*)(fI + (size_t)TOPK * NR);       // 8192

    k1_encode<<<NR/4, 256, 0, stream>>>(xd, xs, Wd, bd, Ws, bs, Wf, bf, Wq, Wk, qh, kh);
    k2A_stats<<<16*128, 256, 0, stream>>>(qh, kh, Mf, Rf);
    k2C_topk<<<4*128, 256, 0, stream>>>(qh, kh, Mf, Rf, fV, fI);
    k3_base<<<NR, 256, 0, stream>>>(prior, Lout, Aout, deg);
    k4_scatter<<<NR/256, 256, 0, stream>>>(fV, fI, Lout, Aout, deg);
    k5_diag<<<NR/256, 256, 0, stream>>>(deg, Lout);
}